// Round 6
// baseline (122.770 us; speedup 1.0000x reference)
//
#include <hip/hip_runtime.h>
#include <hip/hip_bf16.h>

// BatchedNeRFMLP: B=64, N=16384, HID=128, POS_IN=63 (+bias col -> K=64), DIR_IN=27
// params per batch (TOTAL=8789 fp32):
//   pw [128][63] @0   pb[128]@8064   sw[128]@8192  sb@8320
//   cw [3][155] @8321 cb[3]@8786
// out: sigma (B*N) then rgb (B*N*3), fp32.
//
// Layer-1: mfma_f32_32x32x16_bf16, D[h][ray] (A=weights reg-stationary, B=ENC^T
// via XOR-swizzled LDS). ENC K-order: [x0,x1,x2,1.0, f0:(s0,s1,s2,c0,c1,c2),...f9]
// bias=pb rides k=3 (enc k=3 is constant 1.0).
// Head (sigma,r,g,b; K=128): W2 K-order permuted so each lane's naturally-held
// D-rows are its B-frag k-slots -> repack is relu+pack of own regs, no shuffles.
//
// Occupancy: __launch_bounds__(256,4) -> 4 blocks/CU (VGPR<=128, LDS 128/160KB),
// entire 1024-block grid co-resident, 4 waves/SIMD for latency hiding.
// No __syncthreads: rows are wave-private; per-wave DS ops are in-order.

#define NB 64
#define NRAY 16384
#define NTOTAL 8789
#define PI_F 3.14159265358979323846f

typedef short bf16x8 __attribute__((ext_vector_type(8)));
typedef float f32x16 __attribute__((ext_vector_type(16)));

union U8 { unsigned u[4]; bf16x8 v; };

__device__ __forceinline__ unsigned pk2(float a, float b) {
    float2 t; t.x = a; t.y = b;
    __hip_bfloat162 h = __float22bfloat162_rn(t);   // v_cvt_pk_bf16_f32
    return *reinterpret_cast<unsigned*>(&h);
}

__global__ __launch_bounds__(256, 4) void nerf_mfma_kernel(
    const float* __restrict__ pos,
    const float* __restrict__ dir,
    const float* __restrict__ params,
    float* __restrict__ out)
{
    const int tid  = threadIdx.x;
    const int lane = tid & 63;
    const int wid  = tid >> 6;
    const int hi   = lane >> 5;
    const int l31  = lane & 31;

    const int b     = blockIdx.x >> 4;          // 16 blocks per batch
    const int chunk = (blockIdx.x & 15) << 10;  // 1024 rays per block
    const float* __restrict__ p = params + b * NTOTAL;

    __shared__ uint4 encs[2048];                // 256 rows x 128B, swizzled
    char* encb = reinterpret_cast<char*>(encs);

    // ---------------- register-stationary A-frags --------------------------
    // layer-1: k<3 -> d=k ; k==3 -> pb[h] ; k>=4 -> d=k-1
    bf16x8 aw[4][4];
    #pragma unroll
    for (int mt = 0; mt < 4; ++mt) {
        const int hrow = mt * 32 + l31;
        const float* wrow = p + hrow * 63;
        const float bias = p[8064 + hrow];
        #pragma unroll
        for (int ks = 0; ks < 4; ++ks) {
            U8 u;
            #pragma unroll
            for (int j = 0; j < 4; ++j) {
                const int k0 = ks * 16 + hi * 8 + 2 * j;
                const int k1 = k0 + 1;
                const float e0 = (k0 < 3) ? wrow[k0] : (k0 == 3 ? bias : wrow[k0 - 1]);
                const float e1 = (k1 < 3) ? wrow[k1] : (k1 == 3 ? bias : wrow[k1 - 1]);
                u.u[j] = pk2(e0, e1);
            }
            aw[mt][ks] = u.v;
        }
    }
    // head weights, K permuted: slot(s,hi,i) -> h = 32*(s>>1)+16*(s&1)+4hi+(i&3)+8*(i>>2)
    bf16x8 haw[8];
    {
        const int r = l31 & 3;  // 0=sigma(sw), 1..3 = cw rows
        const float* w2 = (r == 0) ? (p + 8192) : (p + 8321 + (r - 1) * 155);
        #pragma unroll
        for (int s = 0; s < 8; ++s) {
            const int base = 32 * (s >> 1) + 16 * (s & 1) + 4 * hi;
            U8 u;
            #pragma unroll
            for (int j = 0; j < 4; ++j) {
                const int i0 = 2 * j, i1 = 2 * j + 1;
                u.u[j] = pk2(w2[base + (i0 & 3) + 8 * (i0 >> 2)],
                             w2[base + (i1 & 3) + 8 * (i1 >> 2)]);
            }
            haw[s] = u.v;
        }
    }

    f32x16 FZ;
    #pragma unroll
    for (int i = 0; i < 16; ++i) FZ[i] = 0.f;

    const float sb  = p[8320];
    const float cb0 = p[8786], cb1 = p[8787], cb2 = p[8788];
    const float* __restrict__ cwr  = p + 8321 + 128;
    const float* __restrict__ cwg  = p + 8321 + 155 + 128;
    const float* __restrict__ cwb2 = p + 8321 + 310 + 128;

    const int rayBlock = b * NRAY + chunk;
    float* __restrict__ rgbout = out + (long)NB * NRAY;
    const long pb0 = (long)(rayBlock + tid) * 3;

    // encode row `tid` of LDS with this thread's position Pv
    auto encode_row = [&](const float3 Pv) {
        const int swz = (tid & 7) << 4;
        char* myrow = encb + tid * 128;
        float s0, c0, s1, c1, s2, c2;
        __sincosf(Pv.x * PI_F, &s0, &c0);
        __sincosf(Pv.y * PI_F, &s1, &c1);
        __sincosf(Pv.z * PI_F, &s2, &c2);
        unsigned w[32];
        w[0] = pk2(Pv.x, Pv.y);
        w[1] = pk2(Pv.z, 1.0f);
        #pragma unroll
        for (int f = 0; f < 10; ++f) {
            w[2 + 3 * f] = pk2(s0, s1);
            w[3 + 3 * f] = pk2(s2, c0);
            w[4 + 3 * f] = pk2(c1, c2);
            if (f < 9) {
                float t;
                t = 2.f * s0 * c0; c0 = fmaf(-2.f * s0, s0, 1.f); s0 = t;
                t = 2.f * s1 * c1; c1 = fmaf(-2.f * s1, s1, 1.f); s1 = t;
                t = 2.f * s2 * c2; c2 = fmaf(-2.f * s2, s2, 1.f); s2 = t;
            }
        }
        #pragma unroll
        for (int cq = 0; cq < 8; ++cq) {
            uint4 v;
            v.x = w[4 * cq + 0]; v.y = w[4 * cq + 1];
            v.z = w[4 * cq + 2]; v.w = w[4 * cq + 3];
            *reinterpret_cast<uint4*>(myrow + ((cq * 16) ^ swz)) = v;
        }
    };

    // prologue: encode iter-0, prefetch iter-1 pos and iter-0 dir
    float3 P0 = *reinterpret_cast<const float3*>(pos + pb0);
    float3 Pn = *reinterpret_cast<const float3*>(pos + pb0 + 768);
    float3 Dc = *reinterpret_cast<const float3*>(dir + pb0);
    encode_row(P0);

    #pragma unroll 1
    for (int it = 0; it < 4; ++it) {
        const int ray = rayBlock + it * 256 + tid;

        float3 Pn2, Dn;
        if (it < 2) Pn2 = *reinterpret_cast<const float3*>(pos + pb0 + (it + 2) * 768);
        if (it < 3) Dn  = *reinterpret_cast<const float3*>(dir + pb0 + (it + 1) * 768);

        // ---- all 8 B-frag reads first (rows hold enc(it)) ------------------
        bf16x8 be[2][4];
        #pragma unroll
        for (int nt = 0; nt < 2; ++nt) {
            const int row = wid * 64 + nt * 32 + l31;
            const int swz = (row & 7) << 4;
            #pragma unroll
            for (int ks = 0; ks < 4; ++ks)
                be[nt][ks] = *reinterpret_cast<const bf16x8*>(
                    encb + row * 128 + ((ks * 32 + hi * 16) ^ swz));
        }

        // ---- encode(it+1) + writes to same rows (after reads: DS in-order) -
        if (it < 3) encode_row(Pn);

        // ---- layer-1 + head MFMA --------------------------------------------
        __builtin_amdgcn_s_setprio(1);
        float hres[2][4];
        #pragma unroll
        for (int nt = 0; nt < 2; ++nt) {
            f32x16 haccA, haccB;
            #pragma unroll
            for (int mt = 0; mt < 4; ++mt) {
                f32x16 accm = __builtin_amdgcn_mfma_f32_32x32x16_bf16(aw[mt][0], be[nt][0], FZ, 0, 0, 0);
                accm = __builtin_amdgcn_mfma_f32_32x32x16_bf16(aw[mt][1], be[nt][1], accm, 0, 0, 0);
                accm = __builtin_amdgcn_mfma_f32_32x32x16_bf16(aw[mt][2], be[nt][2], accm, 0, 0, 0);
                accm = __builtin_amdgcn_mfma_f32_32x32x16_bf16(aw[mt][3], be[nt][3], accm, 0, 0, 0);

                // relu -> pack own regs (pi-permuted K: no cross-lane exchange)
                #pragma unroll
                for (int t = 0; t < 2; ++t) {
                    const int rb = t * 8;
                    U8 u;
                    #pragma unroll
                    for (int j = 0; j < 4; ++j)
                        u.u[j] = pk2(fmaxf(accm[rb + 2 * j], 0.f),
                                     fmaxf(accm[rb + 2 * j + 1], 0.f));
                    const int s = 2 * mt + t;
                    if (t == 0)
                        haccA = __builtin_amdgcn_mfma_f32_32x32x16_bf16(
                            haw[s], u.v, (mt == 0) ? FZ : haccA, 0, 0, 0);
                    else
                        haccB = __builtin_amdgcn_mfma_f32_32x32x16_bf16(
                            haw[s], u.v, (mt == 0) ? FZ : haccB, 0, 0, 0);
                }
            }
            hres[nt][0] = haccA[0] + haccB[0];
            hres[nt][1] = haccA[1] + haccB[1];
            hres[nt][2] = haccA[2] + haccB[2];
            hres[nt][3] = haccA[3] + haccB[3];
        }
        __builtin_amdgcn_s_setprio(0);

        // ---- per-ray tail: dir-encode folded into head FMAs ----------------
        const float hv0 = hi ? hres[1][0] : hres[0][0];
        const float hv1 = hi ? hres[1][1] : hres[0][1];
        const float hv2 = hi ? hres[1][2] : hres[0][2];
        const float hv3 = hi ? hres[1][3] : hres[0][3];

        float sig = hv0 + sb;
        float cr  = hv1 + cb0;
        float cg  = hv2 + cb1;
        float cbl = hv3 + cb2;

        {
            float s0, c0, s1, c1, s2, c2;
            __sincosf(Dc.x * PI_F, &s0, &c0);
            __sincosf(Dc.y * PI_F, &s1, &c1);
            __sincosf(Dc.z * PI_F, &s2, &c2);
            cr  = fmaf(Dc.x, cwr[0], cr);  cg  = fmaf(Dc.x, cwg[0], cg);  cbl = fmaf(Dc.x, cwb2[0], cbl);
            cr  = fmaf(Dc.y, cwr[1], cr);  cg  = fmaf(Dc.y, cwg[1], cg);  cbl = fmaf(Dc.y, cwb2[1], cbl);
            cr  = fmaf(Dc.z, cwr[2], cr);  cg  = fmaf(Dc.z, cwg[2], cg);  cbl = fmaf(Dc.z, cwb2[2], cbl);
            #pragma unroll
            for (int f = 0; f < 4; ++f) {
                const int j = 3 + 6 * f;
                cr = fmaf(s0, cwr[j+0], cr); cg = fmaf(s0, cwg[j+0], cg); cbl = fmaf(s0, cwb2[j+0], cbl);
                cr = fmaf(s1, cwr[j+1], cr); cg = fmaf(s1, cwg[j+1], cg); cbl = fmaf(s1, cwb2[j+1], cbl);
                cr = fmaf(s2, cwr[j+2], cr); cg = fmaf(s2, cwg[j+2], cg); cbl = fmaf(s2, cwb2[j+2], cbl);
                cr = fmaf(c0, cwr[j+3], cr); cg = fmaf(c0, cwg[j+3], cg); cbl = fmaf(c0, cwb2[j+3], cbl);
                cr = fmaf(c1, cwr[j+4], cr); cg = fmaf(c1, cwg[j+4], cg); cbl = fmaf(c1, cwb2[j+4], cbl);
                cr = fmaf(c2, cwr[j+5], cr); cg = fmaf(c2, cwg[j+5], cg); cbl = fmaf(c2, cwb2[j+5], cbl);
                if (f < 3) {
                    float t;
                    t = 2.f * s0 * c0; c0 = fmaf(-2.f * s0, s0, 1.f); s0 = t;
                    t = 2.f * s1 * c1; c1 = fmaf(-2.f * s1, s1, 1.f); s1 = t;
                    t = 2.f * s2 * c2; c2 = fmaf(-2.f * s2, s2, 1.f); s2 = t;
                }
            }
        }

        cr  = 1.0f / (1.0f + __expf(-cr));
        cg  = 1.0f / (1.0f + __expf(-cg));
        cbl = 1.0f / (1.0f + __expf(-cbl));

        out[ray] = sig;
        float3 rgbv; rgbv.x = cr; rgbv.y = cg; rgbv.z = cbl;
        *reinterpret_cast<float3*>(rgbout + (long)ray * 3) = rgbv;

        Pn = Pn2; Dc = Dn;
    }
}

extern "C" void kernel_launch(void* const* d_in, const int* in_sizes, int n_in,
                              void* d_out, int out_size, void* d_ws, size_t ws_size,
                              hipStream_t stream) {
    const float* pos    = (const float*)d_in[0];
    const float* dirs   = (const float*)d_in[1];
    const float* params = (const float*)d_in[2];
    float* out = (float*)d_out;

    dim3 grid(1024);   // 16 blocks/batch x 64 batches, 1024 rays each
    dim3 block(256);
    nerf_mfma_kernel<<<grid, block, 0, stream>>>(pos, dirs, params, out);
}

// Round 7
// 90.215 us; speedup vs baseline: 1.3609x; 1.3609x over previous
//
#include <hip/hip_runtime.h>
#include <hip/hip_bf16.h>

// BatchedNeRFMLP: B=64, N=16384, HID=128, POS_IN=63 (+bias col -> K=64), DIR_IN=27
// params per batch (TOTAL=8789 fp32):
//   pw [128][63] @0   pb[128]@8064   sw[128]@8192  sb@8320
//   cw [3][155] @8321 cb[3]@8786
// out: sigma (B*N) then rgb (B*N*3), fp32.
//
// Layer-1: mfma_f32_32x32x16_bf16, D[h][ray] (A=weights reg-stationary, B=ENC^T
// via XOR-swizzled LDS). ENC K-order: [x0,x1,x2,1.0, f0:(s0,s1,s2,c0,c1,c2),...f9]
// bias=pb rides k=3 (enc k=3 is constant 1.0).
// Head (sigma,r,g,b; K=128): W2 K-order permuted so each lane's naturally-held
// D-rows are its B-frag k-slots -> repack is relu+pack of own regs, no shuffles.
// Head A-frags live in LDS (1KB, per-lane entry = f(s, hi, l31&3)) to cut 32
// permanent VGPRs; r6 lesson: total unified VGPR+AGPR (~200) was pinning us to
// 2 waves/SIMD. Target 3 waves/SIMD: launch_bounds(256,3) after shedding ~60
// regs (haw->LDS, single hacc chain, rolling encode buffer).
// No __syncthreads in the loop: enc rows are wave-private; per-wave DS ops are
// in-order (reads of iter it precede writes of it+1 in program order).

#define NB 64
#define NRAY 16384
#define NTOTAL 8789
#define PI_F 3.14159265358979323846f

typedef short bf16x8 __attribute__((ext_vector_type(8)));
typedef float f32x16 __attribute__((ext_vector_type(16)));

union U8 { unsigned u[4]; bf16x8 v; };

__device__ __forceinline__ unsigned pk2(float a, float b) {
    float2 t; t.x = a; t.y = b;
    __hip_bfloat162 h = __float22bfloat162_rn(t);   // v_cvt_pk_bf16_f32
    return *reinterpret_cast<unsigned*>(&h);
}

__global__ __launch_bounds__(256, 3) void nerf_mfma_kernel(
    const float* __restrict__ pos,
    const float* __restrict__ dir,
    const float* __restrict__ params,
    float* __restrict__ out)
{
    const int tid  = threadIdx.x;
    const int lane = tid & 63;
    const int wid  = tid >> 6;
    const int hi   = lane >> 5;
    const int l31  = lane & 31;

    const int b     = blockIdx.x >> 5;          // 32 blocks per batch
    const int chunk = (blockIdx.x & 31) << 9;   // 512 rays per block
    const float* __restrict__ p = params + b * NTOTAL;

    __shared__ uint4 encs[2048];                // 256 rows x 128B, swizzled
    __shared__ unsigned hawLds[8 * 2 * 4 * 4];  // [s][hi][r][4 words] = 1KB
    char* encb = reinterpret_cast<char*>(encs);
    const char* hawb = reinterpret_cast<const char*>(hawLds);

    // ---- head-weight fragments into LDS (one-time, 64 threads) ------------
    if (tid < 64) {
        const int s  = tid & 7;
        const int hh = (tid >> 3) & 1;
        const int r  = tid >> 4;                // 0=sigma(sw), 1..3 = cw rows
        const float* w2 = (r == 0) ? (p + 8192) : (p + 8321 + (r - 1) * 155);
        const int base = 32 * (s >> 1) + 16 * (s & 1) + 4 * hh;
        unsigned* dst = &hawLds[(((s << 1) + hh) * 4 + r) * 4];
        #pragma unroll
        for (int j = 0; j < 4; ++j) {
            const int i0 = 2 * j, i1 = 2 * j + 1;
            dst[j] = pk2(w2[base + (i0 & 3) + 8 * (i0 >> 2)],
                         w2[base + (i1 & 3) + 8 * (i1 >> 2)]);
        }
    }

    // ---- layer-1 A-frags, register-stationary ------------------------------
    // k<3 -> d=k ; k==3 -> pb[h] ; k>=4 -> d=k-1
    bf16x8 aw[4][4];
    #pragma unroll
    for (int mt = 0; mt < 4; ++mt) {
        const int hrow = mt * 32 + l31;
        const float* wrow = p + hrow * 63;
        const float bias = p[8064 + hrow];
        #pragma unroll
        for (int ks = 0; ks < 4; ++ks) {
            U8 u;
            #pragma unroll
            for (int j = 0; j < 4; ++j) {
                const int k0 = ks * 16 + hi * 8 + 2 * j;
                const int k1 = k0 + 1;
                const float e0 = (k0 < 3) ? wrow[k0] : (k0 == 3 ? bias : wrow[k0 - 1]);
                const float e1 = (k1 < 3) ? wrow[k1] : (k1 == 3 ? bias : wrow[k1 - 1]);
                u.u[j] = pk2(e0, e1);
            }
            aw[mt][ks] = u.v;
        }
    }

    f32x16 FZ;
    #pragma unroll
    for (int i = 0; i < 16; ++i) FZ[i] = 0.f;

    const float sb  = p[8320];
    const float cb0 = p[8786], cb1 = p[8787], cb2 = p[8788];
    const float* __restrict__ cwr  = p + 8321 + 128;
    const float* __restrict__ cwg  = p + 8321 + 155 + 128;
    const float* __restrict__ cwb2 = p + 8321 + 310 + 128;

    const int rayBlock = b * NRAY + chunk;
    float* __restrict__ rgbout = out + (long)NB * NRAY;
    const long pb0 = (long)(rayBlock + tid) * 3;
    const int hoff = hi * 64 + (l31 & 3) * 16;   // byte offset into hawLds s-block

    // encode row `tid` of LDS with position Pv (rolling 4-word buffer)
    auto encode_row = [&](const float3 Pv) {
        const int swz = (tid & 7) << 4;
        char* myrow = encb + tid * 128;
        float s0, c0, s1, c1, s2, c2;
        __sincosf(Pv.x * PI_F, &s0, &c0);
        __sincosf(Pv.y * PI_F, &s1, &c1);
        __sincosf(Pv.z * PI_F, &s2, &c2);
        unsigned wb[4];
        wb[0] = pk2(Pv.x, Pv.y);
        wb[1] = pk2(Pv.z, 1.0f);
        #pragma unroll
        for (int f = 0; f < 10; ++f) {
            const int w = 2 + 3 * f;
            wb[(w + 0) & 3] = pk2(s0, s1);
            if (((w + 0) & 3) == 3) {
                uint4 v; v.x = wb[0]; v.y = wb[1]; v.z = wb[2]; v.w = wb[3];
                *reinterpret_cast<uint4*>(myrow + ((((w + 0) >> 2) * 16) ^ swz)) = v;
            }
            wb[(w + 1) & 3] = pk2(s2, c0);
            if (((w + 1) & 3) == 3) {
                uint4 v; v.x = wb[0]; v.y = wb[1]; v.z = wb[2]; v.w = wb[3];
                *reinterpret_cast<uint4*>(myrow + ((((w + 1) >> 2) * 16) ^ swz)) = v;
            }
            wb[(w + 2) & 3] = pk2(c1, c2);
            if (((w + 2) & 3) == 3) {
                uint4 v; v.x = wb[0]; v.y = wb[1]; v.z = wb[2]; v.w = wb[3];
                *reinterpret_cast<uint4*>(myrow + ((((w + 2) >> 2) * 16) ^ swz)) = v;
            }
            if (f < 9) {
                float t;
                t = 2.f * s0 * c0; c0 = fmaf(-2.f * s0, s0, 1.f); s0 = t;
                t = 2.f * s1 * c1; c1 = fmaf(-2.f * s1, s1, 1.f); s1 = t;
                t = 2.f * s2 * c2; c2 = fmaf(-2.f * s2, s2, 1.f); s2 = t;
            }
        }
    };

    // prologue: prefetch both iterations' inputs, encode iter-0
    float3 Pc = *reinterpret_cast<const float3*>(pos + pb0);
    float3 Pn = *reinterpret_cast<const float3*>(pos + pb0 + 768);
    float3 Dc = *reinterpret_cast<const float3*>(dir + pb0);
    float3 Dn = *reinterpret_cast<const float3*>(dir + pb0 + 768);
    encode_row(Pc);
    __syncthreads();    // hawLds ready (encs rows are wave-private anyway)

    #pragma unroll 1
    for (int it = 0; it < 2; ++it) {
        const int ray = rayBlock + it * 256 + tid;

        // ---- all 8 B-frag reads first (rows hold enc(it)) ------------------
        bf16x8 be[2][4];
        #pragma unroll
        for (int nt = 0; nt < 2; ++nt) {
            const int row = wid * 64 + nt * 32 + l31;
            const int swz = (row & 7) << 4;
            #pragma unroll
            for (int ks = 0; ks < 4; ++ks)
                be[nt][ks] = *reinterpret_cast<const bf16x8*>(
                    encb + row * 128 + ((ks * 32 + hi * 16) ^ swz));
        }

        // ---- encode(it+1) + writes to same rows (after reads: DS in-order) -
        if (it < 1) encode_row(Pn);

        // ---- layer-1 + head MFMA -------------------------------------------
        __builtin_amdgcn_s_setprio(1);
        float hres[2][4];
        #pragma unroll
        for (int nt = 0; nt < 2; ++nt) {
            f32x16 hacc;
            #pragma unroll
            for (int mt = 0; mt < 4; ++mt) {
                f32x16 accm = __builtin_amdgcn_mfma_f32_32x32x16_bf16(aw[mt][0], be[nt][0], FZ, 0, 0, 0);
                accm = __builtin_amdgcn_mfma_f32_32x32x16_bf16(aw[mt][1], be[nt][1], accm, 0, 0, 0);
                accm = __builtin_amdgcn_mfma_f32_32x32x16_bf16(aw[mt][2], be[nt][2], accm, 0, 0, 0);
                accm = __builtin_amdgcn_mfma_f32_32x32x16_bf16(aw[mt][3], be[nt][3], accm, 0, 0, 0);

                // relu -> pack own regs (pi-permuted K), head A-frag from LDS
                #pragma unroll
                for (int t = 0; t < 2; ++t) {
                    const int rb = t * 8;
                    U8 u;
                    #pragma unroll
                    for (int j = 0; j < 4; ++j)
                        u.u[j] = pk2(fmaxf(accm[rb + 2 * j], 0.f),
                                     fmaxf(accm[rb + 2 * j + 1], 0.f));
                    const int s = 2 * mt + t;
                    const bf16x8 hw = *reinterpret_cast<const bf16x8*>(
                        hawb + s * 128 + hoff);
                    hacc = __builtin_amdgcn_mfma_f32_32x32x16_bf16(
                        hw, u.v, (s == 0) ? FZ : hacc, 0, 0, 0);
                }
            }
            hres[nt][0] = hacc[0]; hres[nt][1] = hacc[1];
            hres[nt][2] = hacc[2]; hres[nt][3] = hacc[3];
        }
        __builtin_amdgcn_s_setprio(0);

        // ---- per-ray tail: dir-encode folded into head FMAs ----------------
        const float hv0 = hi ? hres[1][0] : hres[0][0];
        const float hv1 = hi ? hres[1][1] : hres[0][1];
        const float hv2 = hi ? hres[1][2] : hres[0][2];
        const float hv3 = hi ? hres[1][3] : hres[0][3];

        float sig = hv0 + sb;
        float cr  = hv1 + cb0;
        float cg  = hv2 + cb1;
        float cbl = hv3 + cb2;

        {
            float s0, c0, s1, c1, s2, c2;
            __sincosf(Dc.x * PI_F, &s0, &c0);
            __sincosf(Dc.y * PI_F, &s1, &c1);
            __sincosf(Dc.z * PI_F, &s2, &c2);
            cr  = fmaf(Dc.x, cwr[0], cr);  cg  = fmaf(Dc.x, cwg[0], cg);  cbl = fmaf(Dc.x, cwb2[0], cbl);
            cr  = fmaf(Dc.y, cwr[1], cr);  cg  = fmaf(Dc.y, cwg[1], cg);  cbl = fmaf(Dc.y, cwb2[1], cbl);
            cr  = fmaf(Dc.z, cwr[2], cr);  cg  = fmaf(Dc.z, cwg[2], cg);  cbl = fmaf(Dc.z, cwb2[2], cbl);
            #pragma unroll
            for (int f = 0; f < 4; ++f) {
                const int j = 3 + 6 * f;
                cr = fmaf(s0, cwr[j+0], cr); cg = fmaf(s0, cwg[j+0], cg); cbl = fmaf(s0, cwb2[j+0], cbl);
                cr = fmaf(s1, cwr[j+1], cr); cg = fmaf(s1, cwg[j+1], cg); cbl = fmaf(s1, cwb2[j+1], cbl);
                cr = fmaf(s2, cwr[j+2], cr); cg = fmaf(s2, cwg[j+2], cg); cbl = fmaf(s2, cwb2[j+2], cbl);
                cr = fmaf(c0, cwr[j+3], cr); cg = fmaf(c0, cwg[j+3], cg); cbl = fmaf(c0, cwb2[j+3], cbl);
                cr = fmaf(c1, cwr[j+4], cr); cg = fmaf(c1, cwg[j+4], cg); cbl = fmaf(c1, cwb2[j+4], cbl);
                cr = fmaf(c2, cwr[j+5], cr); cg = fmaf(c2, cwg[j+5], cg); cbl = fmaf(c2, cwb2[j+5], cbl);
                if (f < 3) {
                    float t;
                    t = 2.f * s0 * c0; c0 = fmaf(-2.f * s0, s0, 1.f); s0 = t;
                    t = 2.f * s1 * c1; c1 = fmaf(-2.f * s1, s1, 1.f); s1 = t;
                    t = 2.f * s2 * c2; c2 = fmaf(-2.f * s2, s2, 1.f); s2 = t;
                }
            }
        }

        cr  = 1.0f / (1.0f + __expf(-cr));
        cg  = 1.0f / (1.0f + __expf(-cg));
        cbl = 1.0f / (1.0f + __expf(-cbl));

        out[ray] = sig;
        float3 rgbv; rgbv.x = cr; rgbv.y = cg; rgbv.z = cbl;
        *reinterpret_cast<float3*>(rgbout + (long)ray * 3) = rgbv;

        Dc = Dn;
    }
}

extern "C" void kernel_launch(void* const* d_in, const int* in_sizes, int n_in,
                              void* d_out, int out_size, void* d_ws, size_t ws_size,
                              hipStream_t stream) {
    const float* pos    = (const float*)d_in[0];
    const float* dirs   = (const float*)d_in[1];
    const float* params = (const float*)d_in[2];
    float* out = (float*)d_out;

    dim3 grid(NB * 32);   // 2048 blocks, 512 rays each (2 iters of 256)
    dim3 block(256);
    nerf_mfma_kernel<<<grid, block, 0, stream>>>(pos, dirs, params, out);
}

// Round 8
// 86.135 us; speedup vs baseline: 1.4253x; 1.0474x over previous
//
#include <hip/hip_runtime.h>
#include <hip/hip_bf16.h>

// BatchedNeRFMLP: B=64, N=16384, HID=128, POS_IN=63 (+bias col -> K=64), DIR_IN=27
// params per batch (TOTAL=8789 fp32):
//   pw [128][63] @0   pb[128]@8064   sw[128]@8192  sb@8320
//   cw [3][155] @8321 cb[3]@8786
// out: sigma (B*N) then rgb (B*N*3), fp32.
//
// Layer-1: mfma_f32_32x32x16_bf16, D[h][ray]; A = PW staged in LDS (16KB,
// pre-swizzled, SHARED by all 4 waves -> frees 64 VGPRs/thread vs r5),
// B = ENC^T in XOR-swizzled LDS. ENC K-order: [x0,x1,x2,1.0, f0:(s,s,s,c,c,c)..f9],
// bias pb rides k=3. Head W2 K-permuted so repack = relu+pack of own regs
// (no shuffles); head A-frags in LDS (1KB).
// r6/r7 lesson: (256,N>2) gives a 512/N-reg granule; live set must fit it or
// scratch spills dominate (r7: WRITE 223MB). With aw->LDS the live set is
// ~140 <= 168 -> (256,3) legal. LDS 49KB x 3 blocks = 147KB <= 160KB.
// No __syncthreads in the loop: enc rows are wave-private; per-wave DS ops
// are in-order (iter-it reads precede iter-it+1 writes in program order).

#define NB 64
#define NRAY 16384
#define NTOTAL 8789
#define PI_F 3.14159265358979323846f

typedef short bf16x8 __attribute__((ext_vector_type(8)));
typedef float f32x16 __attribute__((ext_vector_type(16)));

union U8 { unsigned u[4]; bf16x8 v; };

__device__ __forceinline__ unsigned pk2(float a, float b) {
    float2 t; t.x = a; t.y = b;
    __hip_bfloat162 h = __float22bfloat162_rn(t);   // v_cvt_pk_bf16_f32
    return *reinterpret_cast<unsigned*>(&h);
}

__global__ __launch_bounds__(256, 3) void nerf_mfma_kernel(
    const float* __restrict__ pos,
    const float* __restrict__ dir,
    const float* __restrict__ params,
    float* __restrict__ out)
{
    const int tid  = threadIdx.x;
    const int lane = tid & 63;
    const int wid  = tid >> 6;
    const int hi   = lane >> 5;
    const int l31  = lane & 31;

    const int b     = blockIdx.x >> 5;          // 32 blocks per batch
    const int chunk = (blockIdx.x & 31) << 9;   // 512 rays per block
    const float* __restrict__ p = params + b * NTOTAL;

    __shared__ uint4 encs[2048];                // 256 rows x 128B, swizzled
    __shared__ uint4 awT[1024];                 // 128 rows x 128B, swizzled
    __shared__ unsigned hawLds[8 * 2 * 4 * 4];  // [s][hi][r][4 words] = 1KB
    char* encb = reinterpret_cast<char*>(encs);
    const char* awb  = reinterpret_cast<const char*>(awT);
    const char* hawb = reinterpret_cast<const char*>(hawLds);

    // ---- head-weight fragments into LDS (one-time, 64 threads) ------------
    if (tid < 64) {
        const int s  = tid & 7;
        const int hh = (tid >> 3) & 1;
        const int r  = tid >> 4;                // 0=sigma(sw), 1..3 = cw rows
        const float* w2 = (r == 0) ? (p + 8192) : (p + 8321 + (r - 1) * 155);
        const int base = 32 * (s >> 1) + 16 * (s & 1) + 4 * hh;
        unsigned* dst = &hawLds[(((s << 1) + hh) * 4 + r) * 4];
        #pragma unroll
        for (int j = 0; j < 4; ++j) {
            const int i0 = 2 * j, i1 = 2 * j + 1;
            dst[j] = pk2(w2[base + (i0 & 3) + 8 * (i0 >> 2)],
                         w2[base + (i1 & 3) + 8 * (i1 >> 2)]);
        }
    }

    // ---- layer-1 A tile into LDS (one-time, shared by all waves) ----------
    // row h: K-order k<3 -> pw[h][k]; k==3 -> pb[h]; k>=4 -> pw[h][k-1]
    {
        const int h    = tid >> 1;              // 0..127
        const int half = tid & 1;               // chunks 0-3 or 4-7
        const float* wrow = p + h * 63;
        const float bias  = p[8064 + h];
        char* dst = reinterpret_cast<char*>(awT) + h * 128;
        const int swz = (h & 7) << 4;
        #pragma unroll
        for (int c4 = 0; c4 < 4; ++c4) {
            const int c = half * 4 + c4;
            U8 u;
            #pragma unroll
            for (int j = 0; j < 4; ++j) {
                const int k0 = 8 * c + 2 * j, k1 = k0 + 1;
                const float e0 = (k0 < 3) ? wrow[k0] : (k0 == 3 ? bias : wrow[k0 - 1]);
                const float e1 = (k1 < 3) ? wrow[k1] : (k1 == 3 ? bias : wrow[k1 - 1]);
                u.u[j] = pk2(e0, e1);
            }
            *reinterpret_cast<uint4*>(dst + ((c * 16) ^ swz)) =
                *reinterpret_cast<uint4*>(&u);
        }
    }

    f32x16 FZ;
    #pragma unroll
    for (int i = 0; i < 16; ++i) FZ[i] = 0.f;

    const float sb  = p[8320];
    const float cb0 = p[8786], cb1 = p[8787], cb2 = p[8788];
    const float* __restrict__ cwr  = p + 8321 + 128;
    const float* __restrict__ cwg  = p + 8321 + 155 + 128;
    const float* __restrict__ cwb2 = p + 8321 + 310 + 128;

    const int rayBlock = b * NRAY + chunk;
    float* __restrict__ rgbout = out + (long)NB * NRAY;
    const long pb0 = (long)(rayBlock + tid) * 3;
    const int hoff = hi * 64 + (l31 & 3) * 16;   // byte offset into hawLds s-block

    // encode row `tid` of LDS with position Pv (rolling 4-word buffer)
    auto encode_row = [&](const float3 Pv) {
        const int swz = (tid & 7) << 4;
        char* myrow = encb + tid * 128;
        float s0, c0, s1, c1, s2, c2;
        __sincosf(Pv.x * PI_F, &s0, &c0);
        __sincosf(Pv.y * PI_F, &s1, &c1);
        __sincosf(Pv.z * PI_F, &s2, &c2);
        unsigned wb[4];
        wb[0] = pk2(Pv.x, Pv.y);
        wb[1] = pk2(Pv.z, 1.0f);
        #pragma unroll
        for (int f = 0; f < 10; ++f) {
            const int w = 2 + 3 * f;
            wb[(w + 0) & 3] = pk2(s0, s1);
            if (((w + 0) & 3) == 3) {
                uint4 v; v.x = wb[0]; v.y = wb[1]; v.z = wb[2]; v.w = wb[3];
                *reinterpret_cast<uint4*>(myrow + ((((w + 0) >> 2) * 16) ^ swz)) = v;
            }
            wb[(w + 1) & 3] = pk2(s2, c0);
            if (((w + 1) & 3) == 3) {
                uint4 v; v.x = wb[0]; v.y = wb[1]; v.z = wb[2]; v.w = wb[3];
                *reinterpret_cast<uint4*>(myrow + ((((w + 1) >> 2) * 16) ^ swz)) = v;
            }
            wb[(w + 2) & 3] = pk2(c1, c2);
            if (((w + 2) & 3) == 3) {
                uint4 v; v.x = wb[0]; v.y = wb[1]; v.z = wb[2]; v.w = wb[3];
                *reinterpret_cast<uint4*>(myrow + ((((w + 2) >> 2) * 16) ^ swz)) = v;
            }
            if (f < 9) {
                float t;
                t = 2.f * s0 * c0; c0 = fmaf(-2.f * s0, s0, 1.f); s0 = t;
                t = 2.f * s1 * c1; c1 = fmaf(-2.f * s1, s1, 1.f); s1 = t;
                t = 2.f * s2 * c2; c2 = fmaf(-2.f * s2, s2, 1.f); s2 = t;
            }
        }
    };

    // prologue: prefetch both iterations' inputs, encode iter-0
    float3 Pc = *reinterpret_cast<const float3*>(pos + pb0);
    float3 Pn = *reinterpret_cast<const float3*>(pos + pb0 + 768);
    float3 Dc = *reinterpret_cast<const float3*>(dir + pb0);
    float3 Dn = *reinterpret_cast<const float3*>(dir + pb0 + 768);
    encode_row(Pc);
    __syncthreads();    // awT + hawLds ready (encs rows are wave-private)

    #pragma unroll 1
    for (int it = 0; it < 2; ++it) {
        const int ray = rayBlock + it * 256 + tid;

        // ---- all 8 B-frag reads first (rows hold enc(it)) ------------------
        bf16x8 be[2][4];
        #pragma unroll
        for (int nt = 0; nt < 2; ++nt) {
            const int row = wid * 64 + nt * 32 + l31;
            const int swz = (row & 7) << 4;
            #pragma unroll
            for (int ks = 0; ks < 4; ++ks)
                be[nt][ks] = *reinterpret_cast<const bf16x8*>(
                    encb + row * 128 + ((ks * 32 + hi * 16) ^ swz));
        }

        // ---- encode(it+1) + writes to same rows (after reads: DS in-order) -
        if (it < 1) encode_row(Pn);

        // ---- layer-1 + head MFMA, mt-outer so A-frags are read once --------
        __builtin_amdgcn_s_setprio(1);
        f32x16 hacc0, hacc1;
        #pragma unroll
        for (int mt = 0; mt < 4; ++mt) {
            const int arow = mt * 32 + l31;
            const int aswz = (arow & 7) << 4;
            bf16x8 awf[4];
            #pragma unroll
            for (int ks = 0; ks < 4; ++ks)
                awf[ks] = *reinterpret_cast<const bf16x8*>(
                    awb + arow * 128 + ((ks * 32 + hi * 16) ^ aswz));

            #pragma unroll
            for (int nt = 0; nt < 2; ++nt) {
                f32x16 accm = __builtin_amdgcn_mfma_f32_32x32x16_bf16(awf[0], be[nt][0], FZ, 0, 0, 0);
                accm = __builtin_amdgcn_mfma_f32_32x32x16_bf16(awf[1], be[nt][1], accm, 0, 0, 0);
                accm = __builtin_amdgcn_mfma_f32_32x32x16_bf16(awf[2], be[nt][2], accm, 0, 0, 0);
                accm = __builtin_amdgcn_mfma_f32_32x32x16_bf16(awf[3], be[nt][3], accm, 0, 0, 0);

                // relu -> pack own regs (pi-permuted K), head A-frag from LDS
                #pragma unroll
                for (int t = 0; t < 2; ++t) {
                    const int rb = t * 8;
                    U8 u;
                    #pragma unroll
                    for (int j = 0; j < 4; ++j)
                        u.u[j] = pk2(fmaxf(accm[rb + 2 * j], 0.f),
                                     fmaxf(accm[rb + 2 * j + 1], 0.f));
                    const int s = 2 * mt + t;
                    const bf16x8 hw = *reinterpret_cast<const bf16x8*>(
                        hawb + s * 128 + hoff);
                    if (nt == 0)
                        hacc0 = __builtin_amdgcn_mfma_f32_32x32x16_bf16(
                            hw, u.v, (s == 0) ? FZ : hacc0, 0, 0, 0);
                    else
                        hacc1 = __builtin_amdgcn_mfma_f32_32x32x16_bf16(
                            hw, u.v, (s == 0) ? FZ : hacc1, 0, 0, 0);
                }
            }
        }
        __builtin_amdgcn_s_setprio(0);

        // ---- per-ray tail: dir-encode folded into head FMAs ----------------
        const float hv0 = hi ? hacc1[0] : hacc0[0];
        const float hv1 = hi ? hacc1[1] : hacc0[1];
        const float hv2 = hi ? hacc1[2] : hacc0[2];
        const float hv3 = hi ? hacc1[3] : hacc0[3];

        float sig = hv0 + sb;
        float cr  = hv1 + cb0;
        float cg  = hv2 + cb1;
        float cbl = hv3 + cb2;

        {
            float s0, c0, s1, c1, s2, c2;
            __sincosf(Dc.x * PI_F, &s0, &c0);
            __sincosf(Dc.y * PI_F, &s1, &c1);
            __sincosf(Dc.z * PI_F, &s2, &c2);
            cr  = fmaf(Dc.x, cwr[0], cr);  cg  = fmaf(Dc.x, cwg[0], cg);  cbl = fmaf(Dc.x, cwb2[0], cbl);
            cr  = fmaf(Dc.y, cwr[1], cr);  cg  = fmaf(Dc.y, cwg[1], cg);  cbl = fmaf(Dc.y, cwb2[1], cbl);
            cr  = fmaf(Dc.z, cwr[2], cr);  cg  = fmaf(Dc.z, cwg[2], cg);  cbl = fmaf(Dc.z, cwb2[2], cbl);
            #pragma unroll
            for (int f = 0; f < 4; ++f) {
                const int j = 3 + 6 * f;
                cr = fmaf(s0, cwr[j+0], cr); cg = fmaf(s0, cwg[j+0], cg); cbl = fmaf(s0, cwb2[j+0], cbl);
                cr = fmaf(s1, cwr[j+1], cr); cg = fmaf(s1, cwg[j+1], cg); cbl = fmaf(s1, cwb2[j+1], cbl);
                cr = fmaf(s2, cwr[j+2], cr); cg = fmaf(s2, cwg[j+2], cg); cbl = fmaf(s2, cwb2[j+2], cbl);
                cr = fmaf(c0, cwr[j+3], cr); cg = fmaf(c0, cwg[j+3], cg); cbl = fmaf(c0, cwb2[j+3], cbl);
                cr = fmaf(c1, cwr[j+4], cr); cg = fmaf(c1, cwg[j+4], cg); cbl = fmaf(c1, cwb2[j+4], cbl);
                cr = fmaf(c2, cwr[j+5], cr); cg = fmaf(c2, cwg[j+5], cg); cbl = fmaf(c2, cwb2[j+5], cbl);
                if (f < 3) {
                    float t;
                    t = 2.f * s0 * c0; c0 = fmaf(-2.f * s0, s0, 1.f); s0 = t;
                    t = 2.f * s1 * c1; c1 = fmaf(-2.f * s1, s1, 1.f); s1 = t;
                    t = 2.f * s2 * c2; c2 = fmaf(-2.f * s2, s2, 1.f); s2 = t;
                }
            }
        }

        cr  = 1.0f / (1.0f + __expf(-cr));
        cg  = 1.0f / (1.0f + __expf(-cg));
        cbl = 1.0f / (1.0f + __expf(-cbl));

        out[ray] = sig;
        float3 rgbv; rgbv.x = cr; rgbv.y = cg; rgbv.z = cbl;
        *reinterpret_cast<float3*>(rgbout + (long)ray * 3) = rgbv;

        Dc = Dn;
    }
}

extern "C" void kernel_launch(void* const* d_in, const int* in_sizes, int n_in,
                              void* d_out, int out_size, void* d_ws, size_t ws_size,
                              hipStream_t stream) {
    const float* pos    = (const float*)d_in[0];
    const float* dirs   = (const float*)d_in[1];
    const float* params = (const float*)d_in[2];
    float* out = (float*)d_out;

    dim3 grid(NB * 32);   // 2048 blocks, 512 rays each (2 iters of 256)
    dim3 block(256);
    nerf_mfma_kernel<<<grid, block, 0, stream>>>(pos, dirs, params, out);
}

// Round 9
// 59.219 us; speedup vs baseline: 2.0732x; 1.4545x over previous
//
#include <hip/hip_runtime.h>
#include <hip/hip_bf16.h>

// BatchedNeRFMLP: B=64, N=16384, HID=128, POS_IN=63 (+bias col -> K=64), DIR_IN=27
// params per batch (TOTAL=8789 fp32):
//   pw [128][63] @0   pb[128]@8064   sw[128]@8192  sb@8320
//   cw [3][155] @8321 cb[3]@8786
// out: sigma (B*N) then rgb (B*N*3), fp32.
//
// Layer-1: mfma_f32_32x32x16_bf16, D[h][ray]; A = PW reg-stationary,
// B = ENC^T in XOR-swizzled LDS (K-order [x,y,z,1.0, f0:(s,s,s,c,c,c)..f9],
// pb rides k=3). Head K=160 = [128 hidden | 27 dir-enc + bias-slot + pad]:
//   s=0..7: B = relu(h) repacked from own accm regs (W2 K-permuted, no shuffles)
//   s=8..9: B = dir-encoding from LDS (natural k-order); d==27 slot carries 1.0
//           and A carries sb/cb -> ALL biases + dir tail folded into MFMA.
// Trig: v_sin/v_cos take REVOLUTIONS -> sin(pi x) = builtin_sinf(0.5x); kills
// libm __sincosf range-reduction overhead (r8 lesson: VALU-busy 23us dominates).
// Occupancy pinned at (256,2) — r6-r8 proved (256,3+) spills (~200-reg live set).
// No __syncthreads: enc/dir rows are wave-private; per-wave DS ops in-order.

#define NB 64
#define NRAY 16384
#define NTOTAL 8789

typedef short bf16x8 __attribute__((ext_vector_type(8)));
typedef float f32x16 __attribute__((ext_vector_type(16)));

union U8 { unsigned u[4]; bf16x8 v; };

__device__ __forceinline__ unsigned pk2(float a, float b) {
    float2 t; t.x = a; t.y = b;
    __hip_bfloat162 h = __float22bfloat162_rn(t);   // v_cvt_pk_bf16_f32
    return *reinterpret_cast<unsigned*>(&h);
}

__global__ __launch_bounds__(256, 2) void nerf_mfma_kernel(
    const float* __restrict__ pos,
    const float* __restrict__ dir,
    const float* __restrict__ params,
    float* __restrict__ out)
{
    const int tid  = threadIdx.x;
    const int lane = tid & 63;
    const int wid  = tid >> 6;
    const int hi   = lane >> 5;
    const int l31  = lane & 31;

    const int b     = blockIdx.x >> 4;          // 16 blocks per batch
    const int chunk = (blockIdx.x & 15) << 10;  // 1024 rays per block
    const float* __restrict__ p = params + b * NTOTAL;

    __shared__ uint4 encs[2048];                // 256 rows x 128B (pos enc)
    __shared__ uint4 dirs[1024];                // 128 rows x 128B (2 rays/row)
    char* encb = reinterpret_cast<char*>(encs);
    char* dirb = reinterpret_cast<char*>(dirs);

    // ---- layer-1 A-frags, register-stationary ------------------------------
    // k<3 -> d=k ; k==3 -> pb[h] ; k>=4 -> d=k-1
    bf16x8 aw[4][4];
    #pragma unroll
    for (int mt = 0; mt < 4; ++mt) {
        const int hrow = mt * 32 + l31;
        const float* wrow = p + hrow * 63;
        const float bias = p[8064 + hrow];
        #pragma unroll
        for (int ks = 0; ks < 4; ++ks) {
            U8 u;
            #pragma unroll
            for (int j = 0; j < 4; ++j) {
                const int k0 = ks * 16 + hi * 8 + 2 * j;
                const int k1 = k0 + 1;
                const float e0 = (k0 < 3) ? wrow[k0] : (k0 == 3 ? bias : wrow[k0 - 1]);
                const float e1 = (k1 < 3) ? wrow[k1] : (k1 == 3 ? bias : wrow[k1 - 1]);
                u.u[j] = pk2(e0, e1);
            }
            aw[mt][ks] = u.v;
        }
    }

    // ---- head A-frags (10 k-steps, K=160) ----------------------------------
    bf16x8 haw[10];
    {
        const int r = l31 & 3;  // 0=sigma, 1..3 = cw rows
        const float* w2 = (r == 0) ? (p + 8192) : (p + 8321 + (r - 1) * 155);
        // s=0..7: hidden part, K PERMUTED: slot(s,hi,i) -> h=32*(s>>1)+16*(s&1)+4hi+(i&3)+8*(i>>2)
        #pragma unroll
        for (int s = 0; s < 8; ++s) {
            const int base = 32 * (s >> 1) + 16 * (s & 1) + 4 * hi;
            U8 u;
            #pragma unroll
            for (int j = 0; j < 4; ++j) {
                const int i0 = 2 * j, i1 = 2 * j + 1;
                u.u[j] = pk2(w2[base + (i0 & 3) + 8 * (i0 >> 2)],
                             w2[base + (i1 & 3) + 8 * (i1 >> 2)]);
            }
            haw[s] = u.v;
        }
        // s=8..9: dir part, NATURAL k-order; d==27 -> bias; d>27 -> 0
        const float bias2 = (r == 0) ? p[8320] : p[8786 + r - 1];
        #pragma unroll
        for (int s = 8; s < 10; ++s) {
            U8 u;
            #pragma unroll
            for (int j = 0; j < 4; ++j) {
                const int d0 = (s - 8) * 16 + hi * 8 + 2 * j;
                const int d1 = d0 + 1;
                const float e0 = (d0 == 27) ? bias2 : ((d0 < 27 && r > 0) ? w2[128 + d0] : 0.f);
                const float e1 = (d1 == 27) ? bias2 : ((d1 < 27 && r > 0) ? w2[128 + d1] : 0.f);
                u.u[j] = pk2(e0, e1);
            }
            haw[s] = u.v;
        }
    }

    f32x16 FZ;
    #pragma unroll
    for (int i = 0; i < 16; ++i) FZ[i] = 0.f;

    const int rayBlock = b * NRAY + chunk;
    float* __restrict__ rgbout = out + (long)NB * NRAY;
    const long pb0 = (long)(rayBlock + tid) * 3;

    // ---- pos encoding into row `tid` (rolling 4-word buffer) ---------------
    auto encode_row = [&](const float3 Pv) {
        const int swz = (tid & 7) << 4;
        char* myrow = encb + tid * 128;
        float s0 = __builtin_amdgcn_sinf(0.5f * Pv.x), c0 = __builtin_amdgcn_cosf(0.5f * Pv.x);
        float s1 = __builtin_amdgcn_sinf(0.5f * Pv.y), c1 = __builtin_amdgcn_cosf(0.5f * Pv.y);
        float s2 = __builtin_amdgcn_sinf(0.5f * Pv.z), c2 = __builtin_amdgcn_cosf(0.5f * Pv.z);
        unsigned wb[4];
        wb[0] = pk2(Pv.x, Pv.y);
        wb[1] = pk2(Pv.z, 1.0f);
        #pragma unroll
        for (int f = 0; f < 10; ++f) {
            const int w = 2 + 3 * f;
            wb[(w + 0) & 3] = pk2(s0, s1);
            if (((w + 0) & 3) == 3) {
                uint4 v; v.x = wb[0]; v.y = wb[1]; v.z = wb[2]; v.w = wb[3];
                *reinterpret_cast<uint4*>(myrow + ((((w + 0) >> 2) * 16) ^ swz)) = v;
            }
            wb[(w + 1) & 3] = pk2(s2, c0);
            if (((w + 1) & 3) == 3) {
                uint4 v; v.x = wb[0]; v.y = wb[1]; v.z = wb[2]; v.w = wb[3];
                *reinterpret_cast<uint4*>(myrow + ((((w + 1) >> 2) * 16) ^ swz)) = v;
            }
            wb[(w + 2) & 3] = pk2(c1, c2);
            if (((w + 2) & 3) == 3) {
                uint4 v; v.x = wb[0]; v.y = wb[1]; v.z = wb[2]; v.w = wb[3];
                *reinterpret_cast<uint4*>(myrow + ((((w + 2) >> 2) * 16) ^ swz)) = v;
            }
            if (f < 9) {
                float t;
                t = 2.f * s0 * c0; c0 = fmaf(-2.f * s0, s0, 1.f); s0 = t;
                t = 2.f * s1 * c1; c1 = fmaf(-2.f * s1, s1, 1.f); s1 = t;
                t = 2.f * s2 * c2; c2 = fmaf(-2.f * s2, s2, 1.f); s2 = t;
            }
        }
    };

    // ---- dir encoding: 32 bf16 (27 + 1.0 + pad) into half-row tid>>1 -------
    auto encode_dir = [&](const float3 Dv) {
        const int row  = tid >> 1;
        const int half = tid & 1;
        const int dswz = (row & 7) << 4;
        char* base = dirb + row * 128;
        float s0 = __builtin_amdgcn_sinf(0.5f * Dv.x), c0 = __builtin_amdgcn_cosf(0.5f * Dv.x);
        float s1 = __builtin_amdgcn_sinf(0.5f * Dv.y), c1 = __builtin_amdgcn_cosf(0.5f * Dv.y);
        float s2 = __builtin_amdgcn_sinf(0.5f * Dv.z), c2 = __builtin_amdgcn_cosf(0.5f * Dv.z);
        unsigned wd[16];
        wd[0] = pk2(Dv.x, Dv.y);
        wd[1] = pk2(Dv.z, s0);
        wd[2] = pk2(s1, s2);
        wd[3] = pk2(c0, c1);
        float c2p;
        #pragma unroll
        for (int f = 1; f < 4; ++f) {
            c2p = c2;
            float t;
            t = 2.f * s0 * c0; c0 = fmaf(-2.f * s0, s0, 1.f); s0 = t;
            t = 2.f * s1 * c1; c1 = fmaf(-2.f * s1, s1, 1.f); s1 = t;
            t = 2.f * s2 * c2; c2 = fmaf(-2.f * s2, s2, 1.f); s2 = t;
            wd[1 + 3 * f] = pk2(c2p, s0);
            wd[2 + 3 * f] = pk2(s1, s2);
            wd[3 + 3 * f] = pk2(c0, c1);
        }
        wd[13] = pk2(c2, 1.0f);   // d=27 slot = 1.0 -> multiplies bias in A
        wd[14] = 0u;
        wd[15] = 0u;
        #pragma unroll
        for (int c = 0; c < 4; ++c) {
            uint4 v;
            v.x = wd[4 * c + 0]; v.y = wd[4 * c + 1];
            v.z = wd[4 * c + 2]; v.w = wd[4 * c + 3];
            *reinterpret_cast<uint4*>(base + ((half * 64 + c * 16) ^ dswz)) = v;
        }
    };

    // prologue: encode iter-0, prefetch iter-1
    float3 Pc = *reinterpret_cast<const float3*>(pos + pb0);
    float3 Dc = *reinterpret_cast<const float3*>(dir + pb0);
    encode_row(Pc);
    encode_dir(Dc);
    float3 Pn = *reinterpret_cast<const float3*>(pos + pb0 + 768);
    float3 Dn = *reinterpret_cast<const float3*>(dir + pb0 + 768);

    #pragma unroll 1
    for (int it = 0; it < 4; ++it) {
        const int ray = rayBlock + it * 256 + tid;

        float3 Pn2, Dn2;
        if (it < 2) {
            Pn2 = *reinterpret_cast<const float3*>(pos + pb0 + (it + 2) * 768);
            Dn2 = *reinterpret_cast<const float3*>(dir + pb0 + (it + 2) * 768);
        }

        // ---- all B-frag reads first (rows hold enc/dir of iter it) ---------
        bf16x8 be[2][4];
        bf16x8 bd[2][2];
        #pragma unroll
        for (int nt = 0; nt < 2; ++nt) {
            const int rayL = wid * 64 + nt * 32 + l31;
            const int swz = (rayL & 7) << 4;
            #pragma unroll
            for (int ks = 0; ks < 4; ++ks)
                be[nt][ks] = *reinterpret_cast<const bf16x8*>(
                    encb + rayL * 128 + ((ks * 32 + hi * 16) ^ swz));
            const int drow = rayL >> 1, dhalf = rayL & 1;
            const int dswz = (drow & 7) << 4;
            #pragma unroll
            for (int t = 0; t < 2; ++t)
                bd[nt][t] = *reinterpret_cast<const bf16x8*>(
                    dirb + drow * 128 + ((dhalf * 64 + t * 32 + hi * 16) ^ dswz));
        }

        // ---- encode(it+1): writes after reads (per-wave DS in-order) -------
        if (it < 3) {
            encode_dir(Dn);
            encode_row(Pn);
        }

        // ---- layer-1 + head MFMA (K=160) ------------------------------------
        __builtin_amdgcn_s_setprio(1);
        float hres[2][4];
        #pragma unroll
        for (int nt = 0; nt < 2; ++nt) {
            f32x16 haccA, haccB;
            #pragma unroll
            for (int mt = 0; mt < 4; ++mt) {
                f32x16 accm = __builtin_amdgcn_mfma_f32_32x32x16_bf16(aw[mt][0], be[nt][0], FZ, 0, 0, 0);
                accm = __builtin_amdgcn_mfma_f32_32x32x16_bf16(aw[mt][1], be[nt][1], accm, 0, 0, 0);
                accm = __builtin_amdgcn_mfma_f32_32x32x16_bf16(aw[mt][2], be[nt][2], accm, 0, 0, 0);
                accm = __builtin_amdgcn_mfma_f32_32x32x16_bf16(aw[mt][3], be[nt][3], accm, 0, 0, 0);

                // relu -> pack own regs (pi-permuted K: no cross-lane exchange)
                #pragma unroll
                for (int t = 0; t < 2; ++t) {
                    const int rb = t * 8;
                    U8 u;
                    #pragma unroll
                    for (int j = 0; j < 4; ++j)
                        u.u[j] = pk2(fmaxf(accm[rb + 2 * j], 0.f),
                                     fmaxf(accm[rb + 2 * j + 1], 0.f));
                    const int s = 2 * mt + t;
                    if (t == 0)
                        haccA = __builtin_amdgcn_mfma_f32_32x32x16_bf16(
                            haw[s], u.v, (mt == 0) ? FZ : haccA, 0, 0, 0);
                    else
                        haccB = __builtin_amdgcn_mfma_f32_32x32x16_bf16(
                            haw[s], u.v, (mt == 0) ? FZ : haccB, 0, 0, 0);
                }
            }
            // dir-enc k-steps (s=8,9): biases ride the d=27 slot
            haccA = __builtin_amdgcn_mfma_f32_32x32x16_bf16(haw[8], bd[nt][0], haccA, 0, 0, 0);
            haccB = __builtin_amdgcn_mfma_f32_32x32x16_bf16(haw[9], bd[nt][1], haccB, 0, 0, 0);

            hres[nt][0] = haccA[0] + haccB[0];
            hres[nt][1] = haccA[1] + haccB[1];
            hres[nt][2] = haccA[2] + haccB[2];
            hres[nt][3] = haccA[3] + haccB[3];
        }
        __builtin_amdgcn_s_setprio(0);

        // ---- per-ray tail: just select + sigmoid ----------------------------
        const float sig = hi ? hres[1][0] : hres[0][0];
        float cr  = hi ? hres[1][1] : hres[0][1];
        float cg  = hi ? hres[1][2] : hres[0][2];
        float cbl = hi ? hres[1][3] : hres[0][3];

        cr  = 1.0f / (1.0f + __expf(-cr));
        cg  = 1.0f / (1.0f + __expf(-cg));
        cbl = 1.0f / (1.0f + __expf(-cbl));

        out[ray] = sig;
        float3 rgbv; rgbv.x = cr; rgbv.y = cg; rgbv.z = cbl;
        *reinterpret_cast<float3*>(rgbout + (long)ray * 3) = rgbv;

        Pn = Pn2; Dn = Dn2;
    }
}

extern "C" void kernel_launch(void* const* d_in, const int* in_sizes, int n_in,
                              void* d_out, int out_size, void* d_ws, size_t ws_size,
                              hipStream_t stream) {
    const float* pos    = (const float*)d_in[0];
    const float* dirs   = (const float*)d_in[1];
    const float* params = (const float*)d_in[2];
    float* out = (float*)d_out;

    dim3 grid(1024);   // 16 blocks/batch x 64 batches, 1024 rays each
    dim3 block(256);
    nerf_mfma_kernel<<<grid, block, 0, stream>>>(pos, dirs, params, out);
}

// Round 10
// 56.220 us; speedup vs baseline: 2.1837x; 1.0533x over previous
//
#include <hip/hip_runtime.h>
#include <hip/hip_bf16.h>

// BatchedNeRFMLP: B=64, N=16384, HID=128, POS_IN=63 (+bias col -> K=64), DIR_IN=27
// params per batch (TOTAL=8789 fp32):
//   pw [128][63] @0   pb[128]@8064   sw[128]@8192  sb@8320
//   cw [3][155] @8321 cb[3]@8786
// out: sigma (B*N) then rgb (B*N*3), fp32.
//
// r5 skeleton (best 53.7us) + 3-waves/SIMD register diet:
//   - layer-1 A tile in LDS (16KB, pre-swizzled, shared by all waves)  [r8-verified]
//   - head W2 frags in LDS (1KB)                                       [r7-verified]
//   - be read per-nt (16 live regs, not 32); encode(it+1) placed between
//     nt1 reads and nt1 MFMA (reads precede writes; per-wave DS in-order)
//   - single hacc chain; acc side = hacc16+accm16+FZ16 = 48
// r6-r9 lesson: (256,3) splits the 168-reg granule ~84 arch + ~84 acc; the
// ARCH side must fit (r8 failed with be32+awf16 up front -> spills). Here
// arch ~= 70-80. Tripwire: WRITE_SIZE >> 16MB means spill -> revert to (256,2).
// Trig: v_sin/v_cos take REVOLUTIONS -> sin(pi x) = builtin_sinf(0.5x).
// Scalar dir tail (r9's MFMA dir-fold regressed: longer serial chain).
// No __syncthreads in loop: enc rows wave-private; per-wave DS ops in-order.

#define NB 64
#define NRAY 16384
#define NTOTAL 8789

typedef short bf16x8 __attribute__((ext_vector_type(8)));
typedef float f32x16 __attribute__((ext_vector_type(16)));

union U8 { unsigned u[4]; bf16x8 v; };

__device__ __forceinline__ unsigned pk2(float a, float b) {
    float2 t; t.x = a; t.y = b;
    __hip_bfloat162 h = __float22bfloat162_rn(t);   // v_cvt_pk_bf16_f32
    return *reinterpret_cast<unsigned*>(&h);
}

__global__ __launch_bounds__(256, 3) void nerf_mfma_kernel(
    const float* __restrict__ pos,
    const float* __restrict__ dir,
    const float* __restrict__ params,
    float* __restrict__ out)
{
    const int tid  = threadIdx.x;
    const int lane = tid & 63;
    const int wid  = tid >> 6;
    const int hi   = lane >> 5;
    const int l31  = lane & 31;

    const int b     = blockIdx.x >> 5;          // 32 blocks per batch
    const int chunk = (blockIdx.x & 31) << 9;   // 512 rays per block
    const float* __restrict__ p = params + b * NTOTAL;

    __shared__ uint4 encs[2048];                // 256 rows x 128B, swizzled
    __shared__ uint4 awT[1024];                 // 128 rows x 128B, swizzled
    __shared__ unsigned hawLds[256];            // [s][hi][r][4 words] = 1KB
    char* encb = reinterpret_cast<char*>(encs);
    const char* awb  = reinterpret_cast<const char*>(awT);
    const char* hawb = reinterpret_cast<const char*>(hawLds);

    // ---- head-weight fragments into LDS (one-time, 64 threads) ------------
    if (tid < 64) {
        const int s  = tid & 7;
        const int hh = (tid >> 3) & 1;
        const int r  = tid >> 4;                // 0=sigma(sw), 1..3 = cw rows
        const float* w2 = (r == 0) ? (p + 8192) : (p + 8321 + (r - 1) * 155);
        const int base = 32 * (s >> 1) + 16 * (s & 1) + 4 * hh;
        unsigned* dst = &hawLds[(((s << 1) + hh) * 4 + r) * 4];
        #pragma unroll
        for (int j = 0; j < 4; ++j) {
            const int i0 = 2 * j, i1 = 2 * j + 1;
            dst[j] = pk2(w2[base + (i0 & 3) + 8 * (i0 >> 2)],
                         w2[base + (i1 & 3) + 8 * (i1 >> 2)]);
        }
    }

    // ---- layer-1 A tile into LDS (one-time, shared by all waves) ----------
    // K-order: k<3 -> pw[h][k]; k==3 -> pb[h]; k>=4 -> pw[h][k-1]
    {
        const int h    = tid >> 1;              // 0..127
        const int half = tid & 1;
        const float* wrow = p + h * 63;
        const float bias  = p[8064 + h];
        char* dst = reinterpret_cast<char*>(awT) + h * 128;
        const int swz = (h & 7) << 4;
        #pragma unroll
        for (int c4 = 0; c4 < 4; ++c4) {
            const int c = half * 4 + c4;
            U8 u;
            #pragma unroll
            for (int j = 0; j < 4; ++j) {
                const int k0 = 8 * c + 2 * j, k1 = k0 + 1;
                const float e0 = (k0 < 3) ? wrow[k0] : (k0 == 3 ? bias : wrow[k0 - 1]);
                const float e1 = (k1 < 3) ? wrow[k1] : (k1 == 3 ? bias : wrow[k1 - 1]);
                u.u[j] = pk2(e0, e1);
            }
            *reinterpret_cast<uint4*>(dst + ((c * 16) ^ swz)) =
                *reinterpret_cast<uint4*>(&u);
        }
    }

    f32x16 FZ;
    #pragma unroll
    for (int i = 0; i < 16; ++i) FZ[i] = 0.f;

    const float sb  = p[8320];
    const float cb0 = p[8786], cb1 = p[8787], cb2 = p[8788];
    const float* __restrict__ cwr  = p + 8321 + 128;
    const float* __restrict__ cwg  = p + 8321 + 155 + 128;
    const float* __restrict__ cwb2 = p + 8321 + 310 + 128;

    const int rayBlock = b * NRAY + chunk;
    float* __restrict__ rgbout = out + (long)NB * NRAY;
    const long pb0 = (long)(rayBlock + tid) * 3;
    const int hoff = hi * 64 + (l31 & 3) * 16;

    // ---- pos encoding into row `tid` (rolling 4-word buffer) ---------------
    auto encode_row = [&](const float3 Pv) {
        const int swz = (tid & 7) << 4;
        char* myrow = encb + tid * 128;
        float s0 = __builtin_amdgcn_sinf(0.5f * Pv.x), c0 = __builtin_amdgcn_cosf(0.5f * Pv.x);
        float s1 = __builtin_amdgcn_sinf(0.5f * Pv.y), c1 = __builtin_amdgcn_cosf(0.5f * Pv.y);
        float s2 = __builtin_amdgcn_sinf(0.5f * Pv.z), c2 = __builtin_amdgcn_cosf(0.5f * Pv.z);
        unsigned wb[4];
        wb[0] = pk2(Pv.x, Pv.y);
        wb[1] = pk2(Pv.z, 1.0f);
        #pragma unroll
        for (int f = 0; f < 10; ++f) {
            const int w = 2 + 3 * f;
            wb[(w + 0) & 3] = pk2(s0, s1);
            if (((w + 0) & 3) == 3) {
                uint4 v; v.x = wb[0]; v.y = wb[1]; v.z = wb[2]; v.w = wb[3];
                *reinterpret_cast<uint4*>(myrow + ((((w + 0) >> 2) * 16) ^ swz)) = v;
            }
            wb[(w + 1) & 3] = pk2(s2, c0);
            if (((w + 1) & 3) == 3) {
                uint4 v; v.x = wb[0]; v.y = wb[1]; v.z = wb[2]; v.w = wb[3];
                *reinterpret_cast<uint4*>(myrow + ((((w + 1) >> 2) * 16) ^ swz)) = v;
            }
            wb[(w + 2) & 3] = pk2(c1, c2);
            if (((w + 2) & 3) == 3) {
                uint4 v; v.x = wb[0]; v.y = wb[1]; v.z = wb[2]; v.w = wb[3];
                *reinterpret_cast<uint4*>(myrow + ((((w + 2) >> 2) * 16) ^ swz)) = v;
            }
            if (f < 9) {
                float t;
                t = 2.f * s0 * c0; c0 = fmaf(-2.f * s0, s0, 1.f); s0 = t;
                t = 2.f * s1 * c1; c1 = fmaf(-2.f * s1, s1, 1.f); s1 = t;
                t = 2.f * s2 * c2; c2 = fmaf(-2.f * s2, s2, 1.f); s2 = t;
            }
        }
    };

    // ---- one 32-ray output tile: L1 (4 mt) + head, A-frags from LDS --------
    auto run_tile = [&](const bf16x8* be) -> f32x16 {
        f32x16 hacc;
        #pragma unroll
        for (int mt = 0; mt < 4; ++mt) {
            const int arow = mt * 32 + l31;
            const int aswz = (arow & 7) << 4;
            bf16x8 awf[4];
            #pragma unroll
            for (int ks = 0; ks < 4; ++ks)
                awf[ks] = *reinterpret_cast<const bf16x8*>(
                    awb + arow * 128 + ((ks * 32 + hi * 16) ^ aswz));

            f32x16 accm = __builtin_amdgcn_mfma_f32_32x32x16_bf16(awf[0], be[0], FZ, 0, 0, 0);
            accm = __builtin_amdgcn_mfma_f32_32x32x16_bf16(awf[1], be[1], accm, 0, 0, 0);
            accm = __builtin_amdgcn_mfma_f32_32x32x16_bf16(awf[2], be[2], accm, 0, 0, 0);
            accm = __builtin_amdgcn_mfma_f32_32x32x16_bf16(awf[3], be[3], accm, 0, 0, 0);

            // relu -> pack own regs (pi-permuted head K: no cross-lane moves)
            #pragma unroll
            for (int t = 0; t < 2; ++t) {
                const int rb = t * 8;
                U8 u;
                #pragma unroll
                for (int j = 0; j < 4; ++j)
                    u.u[j] = pk2(fmaxf(accm[rb + 2 * j], 0.f),
                                 fmaxf(accm[rb + 2 * j + 1], 0.f));
                const int s = 2 * mt + t;
                const bf16x8 hw = *reinterpret_cast<const bf16x8*>(
                    hawb + s * 128 + hoff);
                hacc = __builtin_amdgcn_mfma_f32_32x32x16_bf16(
                    hw, u.v, (s == 0) ? FZ : hacc, 0, 0, 0);
            }
        }
        return hacc;
    };

    // prologue: all global inputs, encode iter-0
    float3 Pc = *reinterpret_cast<const float3*>(pos + pb0);
    float3 Pn = *reinterpret_cast<const float3*>(pos + pb0 + 768);
    float3 Dc = *reinterpret_cast<const float3*>(dir + pb0);
    float3 Dn = *reinterpret_cast<const float3*>(dir + pb0 + 768);
    encode_row(Pc);
    __syncthreads();    // awT + hawLds ready (encs rows are wave-private)

    #pragma unroll 1
    for (int it = 0; it < 2; ++it) {
        const int ray = rayBlock + it * 256 + tid;
        const int row0 = wid * 64 + l31;

        // ---- nt=0: read frags, compute ------------------------------------
        bf16x8 be[4];
        {
            const int swz = (row0 & 7) << 4;
            #pragma unroll
            for (int ks = 0; ks < 4; ++ks)
                be[ks] = *reinterpret_cast<const bf16x8*>(
                    encb + row0 * 128 + ((ks * 32 + hi * 16) ^ swz));
        }
        __builtin_amdgcn_s_setprio(1);
        f32x16 h0 = run_tile(be);
        __builtin_amdgcn_s_setprio(0);
        float hres0[4] = { h0[0], h0[1], h0[2], h0[3] };

        // ---- nt=1: read frags FIRST, then encode(it+1), then compute -------
        {
            const int row = row0 + 32;
            const int swz = (row & 7) << 4;
            #pragma unroll
            for (int ks = 0; ks < 4; ++ks)
                be[ks] = *reinterpret_cast<const bf16x8*>(
                    encb + row * 128 + ((ks * 32 + hi * 16) ^ swz));
        }
        if (it == 0) encode_row(Pn);   // writes after all reads of iter 0
        __builtin_amdgcn_s_setprio(1);
        f32x16 h1 = run_tile(be);
        __builtin_amdgcn_s_setprio(0);

        // ---- per-ray tail: dir-encode folded into head FMAs ----------------
        const float hv0 = hi ? h1[0] : hres0[0];
        const float hv1 = hi ? h1[1] : hres0[1];
        const float hv2 = hi ? h1[2] : hres0[2];
        const float hv3 = hi ? h1[3] : hres0[3];

        float sig = hv0 + sb;
        float cr  = hv1 + cb0;
        float cg  = hv2 + cb1;
        float cbl = hv3 + cb2;

        {
            float s0 = __builtin_amdgcn_sinf(0.5f * Dc.x), c0 = __builtin_amdgcn_cosf(0.5f * Dc.x);
            float s1 = __builtin_amdgcn_sinf(0.5f * Dc.y), c1 = __builtin_amdgcn_cosf(0.5f * Dc.y);
            float s2 = __builtin_amdgcn_sinf(0.5f * Dc.z), c2 = __builtin_amdgcn_cosf(0.5f * Dc.z);
            cr  = fmaf(Dc.x, cwr[0], cr);  cg  = fmaf(Dc.x, cwg[0], cg);  cbl = fmaf(Dc.x, cwb2[0], cbl);
            cr  = fmaf(Dc.y, cwr[1], cr);  cg  = fmaf(Dc.y, cwg[1], cg);  cbl = fmaf(Dc.y, cwb2[1], cbl);
            cr  = fmaf(Dc.z, cwr[2], cr);  cg  = fmaf(Dc.z, cwg[2], cg);  cbl = fmaf(Dc.z, cwb2[2], cbl);
            #pragma unroll
            for (int f = 0; f < 4; ++f) {
                const int j = 3 + 6 * f;
                cr = fmaf(s0, cwr[j+0], cr); cg = fmaf(s0, cwg[j+0], cg); cbl = fmaf(s0, cwb2[j+0], cbl);
                cr = fmaf(s1, cwr[j+1], cr); cg = fmaf(s1, cwg[j+1], cg); cbl = fmaf(s1, cwb2[j+1], cbl);
                cr = fmaf(s2, cwr[j+2], cr); cg = fmaf(s2, cwg[j+2], cg); cbl = fmaf(s2, cwb2[j+2], cbl);
                cr = fmaf(c0, cwr[j+3], cr); cg = fmaf(c0, cwg[j+3], cg); cbl = fmaf(c0, cwb2[j+3], cbl);
                cr = fmaf(c1, cwr[j+4], cr); cg = fmaf(c1, cwg[j+4], cg); cbl = fmaf(c1, cwb2[j+4], cbl);
                cr = fmaf(c2, cwr[j+5], cr); cg = fmaf(c2, cwg[j+5], cg); cbl = fmaf(c2, cwb2[j+5], cbl);
                if (f < 3) {
                    float t;
                    t = 2.f * s0 * c0; c0 = fmaf(-2.f * s0, s0, 1.f); s0 = t;
                    t = 2.f * s1 * c1; c1 = fmaf(-2.f * s1, s1, 1.f); s1 = t;
                    t = 2.f * s2 * c2; c2 = fmaf(-2.f * s2, s2, 1.f); s2 = t;
                }
            }
        }

        cr  = 1.0f / (1.0f + __expf(-cr));
        cg  = 1.0f / (1.0f + __expf(-cg));
        cbl = 1.0f / (1.0f + __expf(-cbl));

        out[ray] = sig;
        float3 rgbv; rgbv.x = cr; rgbv.y = cg; rgbv.z = cbl;
        *reinterpret_cast<float3*>(rgbout + (long)ray * 3) = rgbv;

        Dc = Dn;
    }
}

extern "C" void kernel_launch(void* const* d_in, const int* in_sizes, int n_in,
                              void* d_out, int out_size, void* d_ws, size_t ws_size,
                              hipStream_t stream) {
    const float* pos    = (const float*)d_in[0];
    const float* dirs   = (const float*)d_in[1];
    const float* params = (const float*)d_in[2];
    float* out = (float*)d_out;

    dim3 grid(NB * 32);   // 2048 blocks, 512 rays each (2 iters of 256)
    dim3 block(256);
    nerf_mfma_kernel<<<grid, block, 0, stream>>>(pos, dirs, params, out);
}

// Round 11
// 50.289 us; speedup vs baseline: 2.4413x; 1.1179x over previous
//
#include <hip/hip_runtime.h>
#include <hip/hip_bf16.h>

// BatchedNeRFMLP: B=64, N=16384, HID=128, POS_IN=63 (+bias col -> K=64), DIR_IN=27
// params per batch (TOTAL=8789 fp32):
//   pw [128][63] @0   pb[128]@8064   sw[128]@8192  sb@8320
//   cw [3][155] @8321 cb[3]@8786
// out: sigma (B*N) then rgb (B*N*3), fp32.
//
// r5 skeleton (best 53.7us, (256,2), aw reg-stationary) + intra-wave ILP:
//   - the two 32-ray nt tiles are MANUALLY INTERLEAVED: 2 independent L1
//     chains + 2 independent head chains in flight (r5 ran them serially;
//     critical path ~12 dependent MFMAs -> ~6). aw/hw A-frags feed both.
//   - dir-tail 81-FMA dot (depends only on Dc) is computed BEFORE the MFMA
//     cluster -> its VALU fills MFMA latency instead of serializing after.
//   - haw -> LDS (r7-verified) pays for the 2nd accumulator set.
//   Register budget at (256,2): aw64+be32+FZ16+accm32+hacc32+transients ~ 225 <= 256.
// r6-r10 lesson (3-for-3): (256,3+) spills ~200-reg live set -> pinned (256,2).
// Tripwire: WRITE_SIZE >> 16MB = spill = revert.
// Trig: v_sin/v_cos take REVOLUTIONS -> sin(pi x) = builtin_sinf(0.5x).
// No __syncthreads in loop: enc rows wave-private; per-wave DS ops in-order
// (iter-it reads precede iter-it+1 writes in program order).

#define NB 64
#define NRAY 16384
#define NTOTAL 8789

typedef short bf16x8 __attribute__((ext_vector_type(8)));
typedef float f32x16 __attribute__((ext_vector_type(16)));

union U8 { unsigned u[4]; bf16x8 v; };

__device__ __forceinline__ unsigned pk2(float a, float b) {
    float2 t; t.x = a; t.y = b;
    __hip_bfloat162 h = __float22bfloat162_rn(t);   // v_cvt_pk_bf16_f32
    return *reinterpret_cast<unsigned*>(&h);
}

#define MFMA __builtin_amdgcn_mfma_f32_32x32x16_bf16

__global__ __launch_bounds__(256, 2) void nerf_mfma_kernel(
    const float* __restrict__ pos,
    const float* __restrict__ dir,
    const float* __restrict__ params,
    float* __restrict__ out)
{
    const int tid  = threadIdx.x;
    const int lane = tid & 63;
    const int wid  = tid >> 6;
    const int hi   = lane >> 5;
    const int l31  = lane & 31;

    const int b     = blockIdx.x >> 4;          // 16 blocks per batch
    const int chunk = (blockIdx.x & 15) << 10;  // 1024 rays per block
    const float* __restrict__ p = params + b * NTOTAL;

    __shared__ uint4 encs[2048];                // 256 rows x 128B, swizzled
    __shared__ unsigned hawLds[256];            // [s][hi][r][4 words] = 1KB
    char* encb = reinterpret_cast<char*>(encs);
    const char* hawb = reinterpret_cast<const char*>(hawLds);

    // ---- head-weight fragments into LDS (one-time, 64 threads) ------------
    // K permuted: slot(s,hh,i) -> h = 32*(s>>1)+16*(s&1)+4*hh+(i&3)+8*(i>>2)
    if (tid < 64) {
        const int s  = tid & 7;
        const int hh = (tid >> 3) & 1;
        const int r  = tid >> 4;                // 0=sigma(sw), 1..3 = cw rows
        const float* w2 = (r == 0) ? (p + 8192) : (p + 8321 + (r - 1) * 155);
        const int base = 32 * (s >> 1) + 16 * (s & 1) + 4 * hh;
        unsigned* dst = &hawLds[(((s << 1) + hh) * 4 + r) * 4];
        #pragma unroll
        for (int j = 0; j < 4; ++j) {
            const int i0 = 2 * j, i1 = 2 * j + 1;
            dst[j] = pk2(w2[base + (i0 & 3) + 8 * (i0 >> 2)],
                         w2[base + (i1 & 3) + 8 * (i1 >> 2)]);
        }
    }

    // ---- layer-1 A-frags, register-stationary ------------------------------
    // k<3 -> d=k ; k==3 -> pb[h] ; k>=4 -> d=k-1
    bf16x8 aw[4][4];
    #pragma unroll
    for (int mt = 0; mt < 4; ++mt) {
        const int hrow = mt * 32 + l31;
        const float* wrow = p + hrow * 63;
        const float bias = p[8064 + hrow];
        #pragma unroll
        for (int ks = 0; ks < 4; ++ks) {
            U8 u;
            #pragma unroll
            for (int j = 0; j < 4; ++j) {
                const int k0 = ks * 16 + hi * 8 + 2 * j;
                const int k1 = k0 + 1;
                const float e0 = (k0 < 3) ? wrow[k0] : (k0 == 3 ? bias : wrow[k0 - 1]);
                const float e1 = (k1 < 3) ? wrow[k1] : (k1 == 3 ? bias : wrow[k1 - 1]);
                u.u[j] = pk2(e0, e1);
            }
            aw[mt][ks] = u.v;
        }
    }

    f32x16 FZ;
    #pragma unroll
    for (int i = 0; i < 16; ++i) FZ[i] = 0.f;

    const float sb  = p[8320];
    const float cb0 = p[8786], cb1 = p[8787], cb2 = p[8788];
    const float* __restrict__ cwr  = p + 8321 + 128;
    const float* __restrict__ cwg  = p + 8321 + 155 + 128;
    const float* __restrict__ cwb2 = p + 8321 + 310 + 128;

    const int rayBlock = b * NRAY + chunk;
    float* __restrict__ rgbout = out + (long)NB * NRAY;
    const long pb0 = (long)(rayBlock + tid) * 3;
    const int hoff = hi * 64 + (l31 & 3) * 16;

    // ---- pos encoding into row `tid` (rolling 4-word buffer) ---------------
    auto encode_row = [&](const float3 Pv) {
        const int swz = (tid & 7) << 4;
        char* myrow = encb + tid * 128;
        float s0 = __builtin_amdgcn_sinf(0.5f * Pv.x), c0 = __builtin_amdgcn_cosf(0.5f * Pv.x);
        float s1 = __builtin_amdgcn_sinf(0.5f * Pv.y), c1 = __builtin_amdgcn_cosf(0.5f * Pv.y);
        float s2 = __builtin_amdgcn_sinf(0.5f * Pv.z), c2 = __builtin_amdgcn_cosf(0.5f * Pv.z);
        unsigned wb[4];
        wb[0] = pk2(Pv.x, Pv.y);
        wb[1] = pk2(Pv.z, 1.0f);
        #pragma unroll
        for (int f = 0; f < 10; ++f) {
            const int w = 2 + 3 * f;
            wb[(w + 0) & 3] = pk2(s0, s1);
            if (((w + 0) & 3) == 3) {
                uint4 v; v.x = wb[0]; v.y = wb[1]; v.z = wb[2]; v.w = wb[3];
                *reinterpret_cast<uint4*>(myrow + ((((w + 0) >> 2) * 16) ^ swz)) = v;
            }
            wb[(w + 1) & 3] = pk2(s2, c0);
            if (((w + 1) & 3) == 3) {
                uint4 v; v.x = wb[0]; v.y = wb[1]; v.z = wb[2]; v.w = wb[3];
                *reinterpret_cast<uint4*>(myrow + ((((w + 1) >> 2) * 16) ^ swz)) = v;
            }
            wb[(w + 2) & 3] = pk2(c1, c2);
            if (((w + 2) & 3) == 3) {
                uint4 v; v.x = wb[0]; v.y = wb[1]; v.z = wb[2]; v.w = wb[3];
                *reinterpret_cast<uint4*>(myrow + ((((w + 2) >> 2) * 16) ^ swz)) = v;
            }
            if (f < 9) {
                float t;
                t = 2.f * s0 * c0; c0 = fmaf(-2.f * s0, s0, 1.f); s0 = t;
                t = 2.f * s1 * c1; c1 = fmaf(-2.f * s1, s1, 1.f); s1 = t;
                t = 2.f * s2 * c2; c2 = fmaf(-2.f * s2, s2, 1.f); s2 = t;
            }
        }
    };

    // prologue: prefetch inputs, encode iter-0
    float3 Pc = *reinterpret_cast<const float3*>(pos + pb0);
    float3 Pn = *reinterpret_cast<const float3*>(pos + pb0 + 768);
    float3 Dc = *reinterpret_cast<const float3*>(dir + pb0);
    float3 Dn = *reinterpret_cast<const float3*>(dir + pb0 + 768);
    encode_row(Pc);
    __syncthreads();    // hawLds ready (encs rows are wave-private)

    #pragma unroll 1
    for (int it = 0; it < 4; ++it) {
        const int ray = rayBlock + it * 256 + tid;

        float3 Pn2, Dn2;
        if (it < 2) {
            Pn2 = *reinterpret_cast<const float3*>(pos + pb0 + (it + 2) * 768);
            Dn2 = *reinterpret_cast<const float3*>(dir + pb0 + (it + 2) * 768);
        }

        // ---- all 8 B-frag reads first (rows hold enc(it)) ------------------
        bf16x8 be0[4], be1[4];
        {
            const int row0 = wid * 64 + l31;
            const int swz0 = (row0 & 7) << 4;
            const int row1 = row0 + 32;
            const int swz1 = (row1 & 7) << 4;
            #pragma unroll
            for (int ks = 0; ks < 4; ++ks) {
                be0[ks] = *reinterpret_cast<const bf16x8*>(
                    encb + row0 * 128 + ((ks * 32 + hi * 16) ^ swz0));
                be1[ks] = *reinterpret_cast<const bf16x8*>(
                    encb + row1 * 128 + ((ks * 32 + hi * 16) ^ swz1));
            }
        }

        // ---- encode(it+1): writes after reads (per-wave DS in-order) -------
        if (it < 3) encode_row(Pn);

        // ---- dir-tail partials: independent of MFMA -> latency filler ------
        float crd = 0.f, cgd = 0.f, cbd = 0.f;
        {
            float s0 = __builtin_amdgcn_sinf(0.5f * Dc.x), c0 = __builtin_amdgcn_cosf(0.5f * Dc.x);
            float s1 = __builtin_amdgcn_sinf(0.5f * Dc.y), c1 = __builtin_amdgcn_cosf(0.5f * Dc.y);
            float s2 = __builtin_amdgcn_sinf(0.5f * Dc.z), c2 = __builtin_amdgcn_cosf(0.5f * Dc.z);
            crd = fmaf(Dc.x, cwr[0], crd);  cgd = fmaf(Dc.x, cwg[0], cgd);  cbd = fmaf(Dc.x, cwb2[0], cbd);
            crd = fmaf(Dc.y, cwr[1], crd);  cgd = fmaf(Dc.y, cwg[1], cgd);  cbd = fmaf(Dc.y, cwb2[1], cbd);
            crd = fmaf(Dc.z, cwr[2], crd);  cgd = fmaf(Dc.z, cwg[2], cgd);  cbd = fmaf(Dc.z, cwb2[2], cbd);
            #pragma unroll
            for (int f = 0; f < 4; ++f) {
                const int j = 3 + 6 * f;
                crd = fmaf(s0, cwr[j+0], crd); cgd = fmaf(s0, cwg[j+0], cgd); cbd = fmaf(s0, cwb2[j+0], cbd);
                crd = fmaf(s1, cwr[j+1], crd); cgd = fmaf(s1, cwg[j+1], cgd); cbd = fmaf(s1, cwb2[j+1], cbd);
                crd = fmaf(s2, cwr[j+2], crd); cgd = fmaf(s2, cwg[j+2], cgd); cbd = fmaf(s2, cwb2[j+2], cbd);
                crd = fmaf(c0, cwr[j+3], crd); cgd = fmaf(c0, cwg[j+3], cgd); cbd = fmaf(c0, cwb2[j+3], cbd);
                crd = fmaf(c1, cwr[j+4], crd); cgd = fmaf(c1, cwg[j+4], cgd); cbd = fmaf(c1, cwb2[j+4], cbd);
                crd = fmaf(c2, cwr[j+5], crd); cgd = fmaf(c2, cwg[j+5], cgd); cbd = fmaf(c2, cwb2[j+5], cbd);
                if (f < 3) {
                    float t;
                    t = 2.f * s0 * c0; c0 = fmaf(-2.f * s0, s0, 1.f); s0 = t;
                    t = 2.f * s1 * c1; c1 = fmaf(-2.f * s1, s1, 1.f); s1 = t;
                    t = 2.f * s2 * c2; c2 = fmaf(-2.f * s2, s2, 1.f); s2 = t;
                }
            }
        }

        // ---- interleaved MFMA region: 2 L1 chains + 2 head chains ----------
        __builtin_amdgcn_s_setprio(1);
        f32x16 hacc0, hacc1;
        #pragma unroll
        for (int mt = 0; mt < 4; ++mt) {
            f32x16 a0 = MFMA(aw[mt][0], be0[0], FZ, 0, 0, 0);
            f32x16 a1 = MFMA(aw[mt][0], be1[0], FZ, 0, 0, 0);
            a0 = MFMA(aw[mt][1], be0[1], a0, 0, 0, 0);
            a1 = MFMA(aw[mt][1], be1[1], a1, 0, 0, 0);
            a0 = MFMA(aw[mt][2], be0[2], a0, 0, 0, 0);
            a1 = MFMA(aw[mt][2], be1[2], a1, 0, 0, 0);
            a0 = MFMA(aw[mt][3], be0[3], a0, 0, 0, 0);
            a1 = MFMA(aw[mt][3], be1[3], a1, 0, 0, 0);

            // relu -> pack own regs (pi-permuted head K: no cross-lane moves)
            #pragma unroll
            for (int t = 0; t < 2; ++t) {
                const int rb = t * 8;
                const int s = 2 * mt + t;
                U8 u0, u1;
                #pragma unroll
                for (int j = 0; j < 4; ++j) {
                    u0.u[j] = pk2(fmaxf(a0[rb + 2 * j], 0.f),
                                  fmaxf(a0[rb + 2 * j + 1], 0.f));
                    u1.u[j] = pk2(fmaxf(a1[rb + 2 * j], 0.f),
                                  fmaxf(a1[rb + 2 * j + 1], 0.f));
                }
                const bf16x8 hw = *reinterpret_cast<const bf16x8*>(
                    hawb + s * 128 + hoff);
                hacc0 = MFMA(hw, u0.v, (s == 0) ? FZ : hacc0, 0, 0, 0);
                hacc1 = MFMA(hw, u1.v, (s == 0) ? FZ : hacc1, 0, 0, 0);
            }
        }
        __builtin_amdgcn_s_setprio(0);

        // ---- per-ray tail: select + bias + dir partial + sigmoid -----------
        const float hv0 = hi ? hacc1[0] : hacc0[0];
        const float hv1 = hi ? hacc1[1] : hacc0[1];
        const float hv2 = hi ? hacc1[2] : hacc0[2];
        const float hv3 = hi ? hacc1[3] : hacc0[3];

        const float sig = hv0 + sb;
        float cr  = hv1 + cb0 + crd;
        float cg  = hv2 + cb1 + cgd;
        float cbl = hv3 + cb2 + cbd;

        cr  = 1.0f / (1.0f + __expf(-cr));
        cg  = 1.0f / (1.0f + __expf(-cg));
        cbl = 1.0f / (1.0f + __expf(-cbl));

        out[ray] = sig;
        float3 rgbv; rgbv.x = cr; rgbv.y = cg; rgbv.z = cbl;
        *reinterpret_cast<float3*>(rgbout + (long)ray * 3) = rgbv;

        Pn = Pn2; Dc = Dn; Dn = Dn2;
    }
}

extern "C" void kernel_launch(void* const* d_in, const int* in_sizes, int n_in,
                              void* d_out, int out_size, void* d_ws, size_t ws_size,
                              hipStream_t stream) {
    const float* pos    = (const float*)d_in[0];
    const float* dirs   = (const float*)d_in[1];
    const float* params = (const float*)d_in[2];
    float* out = (float*)d_out;

    dim3 grid(1024);   // 16 blocks/batch x 64 batches, 1024 rays each
    dim3 block(256);
    nerf_mfma_kernel<<<grid, block, 0, stream>>>(pos, dirs, params, out);
}